// Round 1
// baseline (3715.432 us; speedup 1.0000x reference)
//
#include <hip/hip_runtime.h>
#include <hip/hip_bf16.h>
#include <stdint.h>

typedef unsigned int u32;
typedef unsigned short u16;

#define NN 50000
#define NE 200000
#define WC 576      // 256 fsrc | 256 res | 8 e_src | 8 e_dst | 48 pad

__device__ __forceinline__ float leaky(float x){ return x >= 0.f ? x : 0.2f*x; }
__device__ __forceinline__ float bf2f(u16 u){ return __uint_as_float(((u32)u)<<16); }
__device__ __forceinline__ u16 f2bf(float f){
    u32 u = __float_as_uint(f);
    u32 r = (u + 0x7fffu + ((u>>16)&1u)) >> 16;
    return (u16)r;
}
__device__ __forceinline__ int nt_src(int r){ return (r==0)?0:((r==3)?2:1); }
__device__ __forceinline__ int nt_dst(int r){ return (r==1)?0:((r==2)?2:1); }

// ra[r][512] = rel_emb[r] @ rel_W[r]
__global__ void k_ra(const float* __restrict__ rel_emb, const float* __restrict__ rel_W,
                     float* __restrict__ ra){
    int r = blockIdx.x;
    for (int j = threadIdx.x; j < 512; j += blockDim.x){
        float acc = 0.f;
        for (int i = 0; i < 64; i++) acc += rel_emb[r*64+i] * rel_W[(r*64+i)*512 + j];
        ra[r*512 + j] = acc;
    }
}

// Assemble Wcat[r] (256 x 576): [node_W[s] | res_W[d] | w_src_eff(8) | w_dst_eff(8) | 0-pad]
__global__ void k_wcat(const float* __restrict__ node_W, const float* __restrict__ res_W,
                       const float* __restrict__ ra, float* __restrict__ Wcat){
    int g = blockIdx.x*blockDim.x + threadIdx.x;
    if (g >= 4*256*WC) return;
    int r = g/(256*WC); int rem = g%(256*WC); int k = rem/WC; int col = rem%WC;
    int s = nt_src(r), d = nt_dst(r);
    float v;
    if (col < 256) v = node_W[(s*256+k)*256 + col];
    else if (col < 512) v = res_W[(d*256+k)*256 + (col-256)];
    else if (col < 520){ // e_src weights: ra[h, D:]
        int h = col-512; float a = 0.f;
        for (int dd = 0; dd < 32; dd++) a += node_W[(s*256+k)*256 + h*32+dd] * ra[r*512 + h*64+32+dd];
        v = a;
    } else if (col < 528){ // e_dst weights: ra[h, :D]
        int h = col-520; float a = 0.f;
        for (int dd = 0; dd < 32; dd++) a += node_W[(d*256+k)*256 + h*32+dd] * ra[r*512 + h*64+dd];
        v = a;
    } else v = 0.f;
    Wcat[g] = v;
}

// C(NN x 576) = feat[r] @ Wcat[r]; epilogue splits outputs.
__launch_bounds__(256)
__global__ void k_gemm(const float* __restrict__ feat, const float* __restrict__ Wcat,
                       const float* __restrict__ res_b,
                       u16* __restrict__ fsrc, u16* __restrict__ resb,
                       float* __restrict__ e_src, float* __restrict__ e_dst){
    __shared__ float As[16][68];
    __shared__ float Bs[16][68];
    int r = blockIdx.z;
    int row0 = blockIdx.y*64;
    int col0 = blockIdx.x*64;
    const float* A = feat + (size_t)r*NN*256;
    const float* W = Wcat + r*256*WC;
    int tid = threadIdx.x;
    int tx = tid & 15, ty = tid >> 4;
    int lr  = tid >> 2;        // A: row within tile
    int lk4 = (tid & 3) * 4;   // A: k offset
    int wk  = tid >> 4;        // B: k row
    int wc4 = (tid & 15) * 4;  // B: col offset
    float acc[4][4] = {};
    for (int k0 = 0; k0 < 256; k0 += 16){
        int arow = row0 + lr; if (arow > NN-1) arow = NN-1;
        float4 av = *(const float4*)(A + (size_t)arow*256 + k0 + lk4);
        float4 bv = *(const float4*)(W + (k0+wk)*WC + col0 + wc4);
        __syncthreads();
        As[lk4+0][lr] = av.x; As[lk4+1][lr] = av.y; As[lk4+2][lr] = av.z; As[lk4+3][lr] = av.w;
        Bs[wk][wc4+0] = bv.x; Bs[wk][wc4+1] = bv.y; Bs[wk][wc4+2] = bv.z; Bs[wk][wc4+3] = bv.w;
        __syncthreads();
        #pragma unroll
        for (int kk = 0; kk < 16; kk++){
            float a[4], b[4];
            #pragma unroll
            for (int i = 0; i < 4; i++) a[i] = As[kk][ty*4+i];
            #pragma unroll
            for (int j = 0; j < 4; j++) b[j] = Bs[kk][tx*4+j];
            #pragma unroll
            for (int i = 0; i < 4; i++)
                #pragma unroll
                for (int j = 0; j < 4; j++)
                    acc[i][j] += a[i]*b[j];
        }
    }
    int d = nt_dst(r);
    for (int i = 0; i < 4; i++){
        int row = row0 + ty*4 + i;
        if (row >= NN) break;
        size_t nidx = (size_t)r*NN + row;
        #pragma unroll
        for (int j = 0; j < 4; j++){
            int col = col0 + tx*4 + j;
            float v = acc[i][j];
            if (col < 256)       fsrc[nidx*256 + col] = f2bf(v);
            else if (col < 512)  resb[nidx*256 + (col-256)] = f2bf(v + res_b[d*256 + (col-256)]);
            else if (col < 520)  e_src[nidx*8 + (col-512)] = v;
            else if (col < 528)  e_dst[nidx*8 + (col-520)] = v;
        }
    }
}

// per (edge,h): e = leaky(e_src[src]+e_dst[dst]); atomicMax per dst (monotone uint map)
__global__ void k_edgeA(const float* __restrict__ e_src, const float* __restrict__ e_dst,
                        const int* __restrict__ src_idx, const int* __restrict__ dst_idx,
                        float* __restrict__ e_buf, u32* __restrict__ m_buf){
    int r = blockIdx.y;
    int rem = blockIdx.x*blockDim.x + threadIdx.x;
    if (rem >= NE*8) return;
    int edge = rem >> 3, h = rem & 7;
    int s = src_idx[r*NE+edge], dd = dst_idx[r*NE+edge];
    float e = leaky(e_src[((size_t)r*NN+s)*8 + h] + e_dst[((size_t)r*NN+dd)*8 + h]);
    e_buf[(size_t)r*NE*8 + rem] = e;
    u32 u = __float_as_uint(e);
    u32 key = (u & 0x80000000u) ? ~u : (u | 0x80000000u);
    atomicMax(&m_buf[((size_t)r*NN+dd)*8 + h], key);
}

// per (edge,h): ex = exp(e - m[dst]); atomicAdd denominator
__global__ void k_edgeB(const int* __restrict__ dst_idx, const u32* __restrict__ m_buf,
                        float* __restrict__ e_buf, float* __restrict__ s_buf){
    int r = blockIdx.y;
    int rem = blockIdx.x*blockDim.x + threadIdx.x;
    if (rem >= NE*8) return;
    int edge = rem >> 3, h = rem & 7;
    int dd = dst_idx[r*NE+edge];
    u32 key = m_buf[((size_t)r*NN+dd)*8 + h];
    u32 u = (key & 0x80000000u) ? (key & 0x7fffffffu) : ~key;
    float m = __uint_as_float(u);
    float ex = __expf(e_buf[(size_t)r*NE*8 + rem] - m);
    e_buf[(size_t)r*NE*8 + rem] = ex;
    atomicAdd(&s_buf[((size_t)r*NN+dd)*8 + h], ex);
}

// one wave per edge: msg = fsrc[src]*a, atomicAdd into agg(=d_out)
__launch_bounds__(256)
__global__ void k_edgeC(const float* __restrict__ e_buf, const float* __restrict__ s_buf,
                        const int* __restrict__ src_idx, const int* __restrict__ dst_idx,
                        const u16* __restrict__ fsrc, float* __restrict__ agg){
    int r = blockIdx.y;
    int edge = (blockIdx.x << 2) + (threadIdx.x >> 6);
    if (edge >= NE) return;
    int lane = threadIdx.x & 63;
    int s = src_idx[r*NE+edge], dd = dst_idx[r*NE+edge];
    int h = lane >> 3;
    float a = e_buf[((size_t)r*NE + edge)*8 + h] / s_buf[((size_t)r*NN+dd)*8 + h];
    const u16* fr = fsrc + ((size_t)r*NN+s)*256 + lane*4;
    float* ob = agg + ((size_t)r*NN+dd)*256 + lane*4;
    atomicAdd(ob+0, bf2f(fr[0])*a);
    atomicAdd(ob+1, bf2f(fr[1])*a);
    atomicAdd(ob+2, bf2f(fr[2])*a);
    atomicAdd(ob+3, bf2f(fr[3])*a);
}

// conv = relu(agg)*alpha + res*(1-alpha), in place on d_out
__global__ void k_combine(float* __restrict__ out, const u16* __restrict__ resb,
                          const float* __restrict__ res_alpha){
    int r = blockIdx.y;
    int g = blockIdx.x*blockDim.x + threadIdx.x;   // one per 4 floats
    if (g >= NN*64) return;
    size_t i4 = (size_t)r*NN*256 + (size_t)g*4;
    int d = nt_dst(r);
    float alpha = 1.f/(1.f + __expf(-res_alpha[d]));
    float beta = 1.f - alpha;
    float4 v = *(float4*)(out + i4);
    const u16* rp = resb + i4;
    float4 o;
    o.x = fmaxf(v.x,0.f)*alpha + bf2f(rp[0])*beta;
    o.y = fmaxf(v.y,0.f)*alpha + bf2f(rp[1])*beta;
    o.z = fmaxf(v.z,0.f)*alpha + bf2f(rp[2])*beta;
    o.w = fmaxf(v.w,0.f)*alpha + bf2f(rp[3])*beta;
    *(float4*)(out + i4) = o;
}

// cross-attention over relations {0,3} (dst ntype 1); in place on d_out
__global__ void k_cross(float* __restrict__ out, const float* __restrict__ cross_attn){
    int n = blockIdx.x; int t = threadIdx.x;   // t = h*32 + d
    size_t i0 = (size_t)n*256 + t;
    size_t i3 = (size_t)3*NN*256 + (size_t)n*256 + t;
    float v0 = out[i0], v3 = out[i3];
    float ca0 = cross_attn[t];
    float ca3 = cross_attn[3*256 + t];
    float p00 = v0*ca0, p30 = v3*ca0, p03 = v0*ca3, p33 = v3*ca3;
    #pragma unroll
    for (int m = 16; m >= 1; m >>= 1){
        p00 += __shfl_xor(p00, m, 64);
        p30 += __shfl_xor(p30, m, 64);
        p03 += __shfl_xor(p03, m, 64);
        p33 += __shfl_xor(p33, m, 64);
    }
    // output r=0 uses cross_attn[0]
    float l0 = leaky(p00), l3 = leaky(p30);
    float mm = fmaxf(l0, l3);
    float w0 = __expf(l0-mm), w3 = __expf(l3-mm);
    float o0 = (w0*v0 + w3*v3) / (w0+w3);
    // output r=3 uses cross_attn[3]
    float q0 = leaky(p03), q3 = leaky(p33);
    float mq = fmaxf(q0, q3);
    float u0 = __expf(q0-mq), u3 = __expf(q3-mq);
    float o3 = (u0*v0 + u3*v3) / (u0+u3);
    out[i0] = o0; out[i3] = o3;
}

__global__ void k_relout(const float* __restrict__ rel_emb, const float* __restrict__ prop_W,
                         const float* __restrict__ prop_b, float* __restrict__ out){
    int r = blockIdx.x; int o = threadIdx.x;
    float acc = prop_b[r*256 + o];
    for (int i = 0; i < 64; i++) acc += rel_emb[r*64+i] * prop_W[(r*64+i)*256 + o];
    out[(size_t)4*NN*256 + r*256 + o] = acc;
}

extern "C" void kernel_launch(void* const* d_in, const int* in_sizes, int n_in,
                              void* d_out, int out_size, void* d_ws, size_t ws_size,
                              hipStream_t stream){
    const float* feat      = (const float*)d_in[0];
    const float* rel_emb   = (const float*)d_in[1];
    const float* node_W    = (const float*)d_in[2];
    const float* rel_W     = (const float*)d_in[3];
    const float* res_W     = (const float*)d_in[4];
    const float* res_b     = (const float*)d_in[5];
    const float* res_alpha = (const float*)d_in[6];
    const float* cross_attn= (const float*)d_in[7];
    const float* prop_W    = (const float*)d_in[8];
    const float* prop_b    = (const float*)d_in[9];
    const int* src_idx     = (const int*)d_in[10];
    const int* dst_idx     = (const int*)d_in[11];
    float* out = (float*)d_out;

    char* ws = (char*)d_ws;
    u32*   m_buf = (u32*)  (ws);                 //  6,400,000 B (4,NN,8) u32
    float* s_buf = (float*)(ws + 6400000);       //  6,400,000 B (4,NN,8)
    float* ra    = (float*)(ws + 12800000);      //      8,192 B (4,512)
    float* Wcat  = (float*)(ws + 12808192);      //  2,359,296 B (4,256,576)
    float* e_src = (float*)(ws + 15167488);      //  6,400,000 B (4,NN,8)
    float* e_dst = (float*)(ws + 21567488);      //  6,400,000 B (4,NN,8)
    float* e_buf = (float*)(ws + 27967488);      // 25,600,000 B (4,NE,8)
    u16*   fsrc  = (u16*)  (ws + 53567488);      //102,400,000 B (4,NN,256) bf16
    u16*   resb  = (u16*)  (ws + 155967488);     //102,400,000 B (4,NN,256) bf16
    // total: 258,367,488 B

    hipMemsetAsync(m_buf, 0, 12800000, stream);            // m + s
    hipMemsetAsync(d_out, 0, (size_t)out_size*4, stream);  // agg accumulators

    k_ra<<<4, 256, 0, stream>>>(rel_emb, rel_W, ra);
    k_wcat<<<(4*256*WC)/256, 256, 0, stream>>>(node_W, res_W, ra, Wcat);
    dim3 gg(WC/64, (NN+63)/64, 4);
    k_gemm<<<gg, 256, 0, stream>>>(feat, Wcat, res_b, fsrc, resb, e_src, e_dst);
    dim3 ge((NE*8+255)/256, 4);
    k_edgeA<<<ge, 256, 0, stream>>>(e_src, e_dst, src_idx, dst_idx, e_buf, m_buf);
    k_edgeB<<<ge, 256, 0, stream>>>(dst_idx, m_buf, e_buf, s_buf);
    dim3 gc((NE+3)/4, 4);
    k_edgeC<<<gc, 256, 0, stream>>>(e_buf, s_buf, src_idx, dst_idx, fsrc, out);
    dim3 gm((NN*64+255)/256, 4);
    k_combine<<<gm, 256, 0, stream>>>(out, resb, res_alpha);
    k_cross<<<NN, 256, 0, stream>>>(out, cross_attn);
    k_relout<<<4, 256, 0, stream>>>(rel_emb, prop_W, prop_b, out);
}

// Round 2
// 1174.156 us; speedup vs baseline: 3.1643x; 3.1643x over previous
//
#include <hip/hip_runtime.h>
#include <hip/hip_bf16.h>
#include <stdint.h>

typedef unsigned int u32;
typedef unsigned short u16;

#define NN 50000
#define NE 200000
#define WC 576      // 256 fsrc | 256 res | 8 e_src | 8 e_dst | 48 pad

__device__ __forceinline__ float leaky(float x){ return x >= 0.f ? x : 0.2f*x; }
__device__ __forceinline__ float bf2f(u16 u){ return __uint_as_float(((u32)u)<<16); }
__device__ __forceinline__ u16 f2bf(float f){
    u32 u = __float_as_uint(f);
    u32 r = (u + 0x7fffu + ((u>>16)&1u)) >> 16;
    return (u16)r;
}
__device__ __forceinline__ int nt_src(int r){ return (r==0)?0:((r==3)?2:1); }
__device__ __forceinline__ int nt_dst(int r){ return (r==1)?0:((r==2)?2:1); }

// ra[r][512] = rel_emb[r] @ rel_W[r]
__global__ void k_ra(const float* __restrict__ rel_emb, const float* __restrict__ rel_W,
                     float* __restrict__ ra){
    int r = blockIdx.x;
    for (int j = threadIdx.x; j < 512; j += blockDim.x){
        float acc = 0.f;
        for (int i = 0; i < 64; i++) acc += rel_emb[r*64+i] * rel_W[(r*64+i)*512 + j];
        ra[r*512 + j] = acc;
    }
}

// Assemble Wcat[r] (256 x 576): [node_W[s] | res_W[d] | w_src_eff(8) | w_dst_eff(8) | 0-pad]
__global__ void k_wcat(const float* __restrict__ node_W, const float* __restrict__ res_W,
                       const float* __restrict__ ra, float* __restrict__ Wcat){
    int g = blockIdx.x*blockDim.x + threadIdx.x;
    if (g >= 4*256*WC) return;
    int r = g/(256*WC); int rem = g%(256*WC); int k = rem/WC; int col = rem%WC;
    int s = nt_src(r), d = nt_dst(r);
    float v;
    if (col < 256) v = node_W[(s*256+k)*256 + col];
    else if (col < 512) v = res_W[(d*256+k)*256 + (col-256)];
    else if (col < 520){ // e_src weights: ra[h, D:]
        int h = col-512; float a = 0.f;
        for (int dd = 0; dd < 32; dd++) a += node_W[(s*256+k)*256 + h*32+dd] * ra[r*512 + h*64+32+dd];
        v = a;
    } else if (col < 528){ // e_dst weights: ra[h, :D]
        int h = col-520; float a = 0.f;
        for (int dd = 0; dd < 32; dd++) a += node_W[(d*256+k)*256 + h*32+dd] * ra[r*512 + h*64+dd];
        v = a;
    } else v = 0.f;
    Wcat[g] = v;
}

// C(NN x 576) = feat[r] @ Wcat[r]; epilogue splits outputs.
__launch_bounds__(256)
__global__ void k_gemm(const float* __restrict__ feat, const float* __restrict__ Wcat,
                       const float* __restrict__ res_b,
                       u16* __restrict__ fsrc, u16* __restrict__ resb,
                       float* __restrict__ e_src, float* __restrict__ e_dst){
    __shared__ float As[16][68];
    __shared__ float Bs[16][68];
    int r = blockIdx.z;
    int row0 = blockIdx.y*64;
    int col0 = blockIdx.x*64;
    const float* A = feat + (size_t)r*NN*256;
    const float* W = Wcat + r*256*WC;
    int tid = threadIdx.x;
    int tx = tid & 15, ty = tid >> 4;
    int lr  = tid >> 2;        // A: row within tile
    int lk4 = (tid & 3) * 4;   // A: k offset
    int wk  = tid >> 4;        // B: k row
    int wc4 = (tid & 15) * 4;  // B: col offset
    float acc[4][4] = {};
    for (int k0 = 0; k0 < 256; k0 += 16){
        int arow = row0 + lr; if (arow > NN-1) arow = NN-1;
        float4 av = *(const float4*)(A + (size_t)arow*256 + k0 + lk4);
        float4 bv = *(const float4*)(W + (k0+wk)*WC + col0 + wc4);
        __syncthreads();
        As[lk4+0][lr] = av.x; As[lk4+1][lr] = av.y; As[lk4+2][lr] = av.z; As[lk4+3][lr] = av.w;
        Bs[wk][wc4+0] = bv.x; Bs[wk][wc4+1] = bv.y; Bs[wk][wc4+2] = bv.z; Bs[wk][wc4+3] = bv.w;
        __syncthreads();
        #pragma unroll
        for (int kk = 0; kk < 16; kk++){
            float a[4], b[4];
            #pragma unroll
            for (int i = 0; i < 4; i++) a[i] = As[kk][ty*4+i];
            #pragma unroll
            for (int j = 0; j < 4; j++) b[j] = Bs[kk][tx*4+j];
            #pragma unroll
            for (int i = 0; i < 4; i++)
                #pragma unroll
                for (int j = 0; j < 4; j++)
                    acc[i][j] += a[i]*b[j];
        }
    }
    int d = nt_dst(r);
    for (int i = 0; i < 4; i++){
        int row = row0 + ty*4 + i;
        if (row >= NN) break;
        size_t nidx = (size_t)r*NN + row;
        #pragma unroll
        for (int j = 0; j < 4; j++){
            int col = col0 + tx*4 + j;
            float v = acc[i][j];
            if (col < 256)       fsrc[nidx*256 + col] = f2bf(v);
            else if (col < 512)  resb[nidx*256 + (col-256)] = f2bf(v + res_b[d*256 + (col-256)]);
            else if (col < 520)  e_src[nidx*8 + (col-512)] = v;
            else if (col < 528)  e_dst[nidx*8 + (col-520)] = v;
        }
    }
}

// ---- CSR build: count -> hierarchical scan -> scatter ----

__global__ void k_count(const int* __restrict__ dst_idx, u32* __restrict__ cnt){
    int r = blockIdx.y; int e = blockIdx.x*256 + threadIdx.x;
    if (e >= NE) return;
    atomicAdd(&cnt[r*NN + dst_idx[r*NE+e]], 1u);
}

__global__ void k_scan1(const u32* __restrict__ cnt, u32* __restrict__ bsum){
    int r = blockIdx.y, b = blockIdx.x;
    int i = b*256 + threadIdx.x;
    u32 v = (i < NN) ? cnt[r*NN+i] : 0u;
    #pragma unroll
    for (int off = 1; off < 64; off <<= 1) v += __shfl_xor(v, off, 64);
    __shared__ u32 wsum[4];
    int lane = threadIdx.x & 63, w = threadIdx.x >> 6;
    if (lane == 0) wsum[w] = v;
    __syncthreads();
    if (threadIdx.x == 0) bsum[r*256 + b] = wsum[0]+wsum[1]+wsum[2]+wsum[3];
}

__device__ __forceinline__ u32 block_scan_incl(u32 v){
    __shared__ u32 wsum[4];
    int lane = threadIdx.x & 63, w = threadIdx.x >> 6;
    #pragma unroll
    for (int off = 1; off < 64; off <<= 1){
        u32 t = __shfl_up(v, off, 64);
        if (lane >= off) v += t;
    }
    if (lane == 63) wsum[w] = v;
    __syncthreads();
    u32 add = 0;
    #pragma unroll
    for (int k = 0; k < 4; k++) if (k < w) add += wsum[k];
    return v + add;
}

// exclusive scan of 256 block sums per relation, in place
__global__ void k_scan2(u32* __restrict__ bsum){
    int r = blockIdx.x;
    u32 v = bsum[r*256 + threadIdx.x];
    u32 incl = block_scan_incl(v);
    bsum[r*256 + threadIdx.x] = incl - v;
}

__global__ void k_scan3(const u32* __restrict__ cnt, const u32* __restrict__ bsum,
                        u32* __restrict__ row_ptr){
    int r = blockIdx.y, b = blockIdx.x;
    int i = b*256 + threadIdx.x;
    u32 v = (i < NN) ? cnt[r*NN+i] : 0u;
    u32 incl = block_scan_incl(v);
    if (i < NN) row_ptr[r*(NN+1) + i + 1] = bsum[r*256 + b] + incl;
    if (b == 0 && threadIdx.x == 0) row_ptr[r*(NN+1)] = 0u;
}

// per edge: pos in dst bucket; payload = src + 8 precomputed leaky logits
__global__ void k_scatter(const int* __restrict__ src_idx, const int* __restrict__ dst_idx,
                          const float* __restrict__ e_src, const float* __restrict__ e_dst,
                          const u32* __restrict__ row_ptr, u32* __restrict__ cnt2,
                          u32* __restrict__ src_pack, float* __restrict__ e_pack){
    int r = blockIdx.y; int e = blockIdx.x*256 + threadIdx.x;
    if (e >= NE) return;
    int s = src_idx[r*NE+e], d = dst_idx[r*NE+e];
    u32 pos = row_ptr[r*(NN+1)+d] + atomicAdd(&cnt2[r*NN+d], 1u);
    src_pack[r*NE + pos] = (u32)s;
    const float* es = e_src + ((size_t)r*NN+s)*8;
    const float* ed = e_dst + ((size_t)r*NN+d)*8;
    float* ep = e_pack + ((size_t)(r*NE)+pos)*8;
    #pragma unroll
    for (int h = 0; h < 8; h++) ep[h] = leaky(es[h] + ed[h]);
}

// one wave per (node, rel): inline segment softmax + message aggregation +
// relu + residual gate. Each output row written exactly once, coalesced.
__launch_bounds__(256)
__global__ void k_agg(const u32* __restrict__ row_ptr, const u32* __restrict__ src_pack,
                      const float* __restrict__ e_pack, const u16* __restrict__ fsrc,
                      const u16* __restrict__ resb, const float* __restrict__ res_alpha,
                      float* __restrict__ out){
    int r = blockIdx.y;
    int wid = threadIdx.x >> 6;
    int n = blockIdx.x*4 + wid;
    if (n >= NN) return;
    int l = threadIdx.x & 63;
    u32 p0 = row_ptr[r*(NN+1)+n];
    u32 p1 = row_ptr[r*(NN+1)+n+1];
    int deg = (int)(p1 - p0);

    // phase 1: online (max, sumexp); lane l covers edge stripe (l>>3), head (l&7)
    float m = -1e30f, s = 0.f;
    for (int i = (l>>3); i < deg; i += 8){
        float e = e_pack[((size_t)(r*NE) + p0 + i)*8 + (l&7)];
        float mn = fmaxf(m, e);
        s = s*__expf(m - mn) + __expf(e - mn);
        m = mn;
    }
    // combine the 8 stripes per head (lanes with equal l&7)
    #pragma unroll
    for (int msk = 8; msk < 64; msk <<= 1){
        float m2 = __shfl_xor(m, msk, 64);
        float s2 = __shfl_xor(s, msk, 64);
        float mn = fmaxf(m, m2);
        s = s*__expf(m - mn) + s2*__expf(m2 - mn);
        m = mn;
    }
    // lane h (h<8) now holds (m,s) for head h; redistribute: lane l needs head l>>3
    int h = l >> 3;
    float mh = __shfl(m, h, 64);
    float sh = __shfl(s, h, 64);

    // phase 2: accumulate messages; lane l owns channels l*4..l*4+3 (head l>>3)
    float a0=0.f, a1=0.f, a2=0.f, a3=0.f;
    for (int i = 0; i < deg; i++){
        size_t ep = (size_t)(r*NE) + p0 + i;
        float a = __expf(e_pack[ep*8 + h] - mh) / sh;
        u32 src = src_pack[ep];
        ushort4 f = *(const ushort4*)(fsrc + ((size_t)r*NN+src)*256 + l*4);
        a0 += bf2f(f.x)*a; a1 += bf2f(f.y)*a; a2 += bf2f(f.z)*a; a3 += bf2f(f.w)*a;
    }
    int d = nt_dst(r);
    float alpha = 1.f/(1.f + __expf(-res_alpha[d]));
    float beta = 1.f - alpha;
    ushort4 rv = *(const ushort4*)(resb + ((size_t)r*NN+n)*256 + l*4);
    float4 o;
    o.x = fmaxf(a0,0.f)*alpha + bf2f(rv.x)*beta;
    o.y = fmaxf(a1,0.f)*alpha + bf2f(rv.y)*beta;
    o.z = fmaxf(a2,0.f)*alpha + bf2f(rv.z)*beta;
    o.w = fmaxf(a3,0.f)*alpha + bf2f(rv.w)*beta;
    *(float4*)(out + ((size_t)r*NN+n)*256 + l*4) = o;
}

// cross-attention over relations {0,3} (dst ntype 1); in place on d_out
__global__ void k_cross(float* __restrict__ out, const float* __restrict__ cross_attn){
    int n = blockIdx.x; int t = threadIdx.x;   // t = h*32 + d
    size_t i0 = (size_t)n*256 + t;
    size_t i3 = (size_t)3*NN*256 + (size_t)n*256 + t;
    float v0 = out[i0], v3 = out[i3];
    float ca0 = cross_attn[t];
    float ca3 = cross_attn[3*256 + t];
    float p00 = v0*ca0, p30 = v3*ca0, p03 = v0*ca3, p33 = v3*ca3;
    #pragma unroll
    for (int m = 16; m >= 1; m >>= 1){
        p00 += __shfl_xor(p00, m, 64);
        p30 += __shfl_xor(p30, m, 64);
        p03 += __shfl_xor(p03, m, 64);
        p33 += __shfl_xor(p33, m, 64);
    }
    float l0 = leaky(p00), l3 = leaky(p30);
    float mm = fmaxf(l0, l3);
    float w0 = __expf(l0-mm), w3 = __expf(l3-mm);
    float o0 = (w0*v0 + w3*v3) / (w0+w3);
    float q0 = leaky(p03), q3 = leaky(p33);
    float mq = fmaxf(q0, q3);
    float u0 = __expf(q0-mq), u3 = __expf(q3-mq);
    float o3 = (u0*v0 + u3*v3) / (u0+u3);
    out[i0] = o0; out[i3] = o3;
}

__global__ void k_relout(const float* __restrict__ rel_emb, const float* __restrict__ prop_W,
                         const float* __restrict__ prop_b, float* __restrict__ out){
    int r = blockIdx.x; int o = threadIdx.x;
    float acc = prop_b[r*256 + o];
    for (int i = 0; i < 64; i++) acc += rel_emb[r*64+i] * prop_W[(r*64+i)*256 + o];
    out[(size_t)4*NN*256 + r*256 + o] = acc;
}

extern "C" void kernel_launch(void* const* d_in, const int* in_sizes, int n_in,
                              void* d_out, int out_size, void* d_ws, size_t ws_size,
                              hipStream_t stream){
    const float* feat      = (const float*)d_in[0];
    const float* rel_emb   = (const float*)d_in[1];
    const float* node_W    = (const float*)d_in[2];
    const float* rel_W     = (const float*)d_in[3];
    const float* res_W     = (const float*)d_in[4];
    const float* res_b     = (const float*)d_in[5];
    const float* res_alpha = (const float*)d_in[6];
    const float* cross_attn= (const float*)d_in[7];
    const float* prop_W    = (const float*)d_in[8];
    const float* prop_b    = (const float*)d_in[9];
    const int* src_idx     = (const int*)d_in[10];
    const int* dst_idx     = (const int*)d_in[11];
    float* out = (float*)d_out;

    char* ws = (char*)d_ws;
    u32*   cnt     = (u32*)  (ws);                 //    800,000 B (4,NN)
    u32*   cnt2    = (u32*)  (ws + 800000);        //    800,000 B (4,NN)
    u32*   bsum    = (u32*)  (ws + 1600000);       //      4,096 B (4,256)
    u32*   row_ptr = (u32*)  (ws + 1604096);       //    800,016 B (4,NN+1) -> pad to 800,016
    float* ra      = (float*)(ws + 2404112);       //      8,192 B (4,512)
    float* Wcat    = (float*)(ws + 2412304);       //  2,359,296 B (4,256,576)
    float* e_src   = (float*)(ws + 4771600);       //  6,400,000 B (4,NN,8)
    float* e_dst   = (float*)(ws + 11171600);      //  6,400,000 B (4,NN,8)
    u32*   src_pack= (u32*)  (ws + 17571600);      //  3,200,000 B (4,NE)
    float* e_pack  = (float*)(ws + 20771600);      // 25,600,000 B (4,NE,8)
    u16*   fsrc    = (u16*)  (ws + 46371600);      //102,400,000 B (4,NN,256) bf16
    u16*   resb    = (u16*)  (ws + 148771600);     //102,400,000 B (4,NN,256) bf16
    // total: 251,171,600 B

    hipMemsetAsync(cnt, 0, 1604096, stream);  // cnt + cnt2 + bsum

    k_ra<<<4, 256, 0, stream>>>(rel_emb, rel_W, ra);
    k_wcat<<<(4*256*WC)/256, 256, 0, stream>>>(node_W, res_W, ra, Wcat);
    dim3 gg(WC/64, (NN+63)/64, 4);
    k_gemm<<<gg, 256, 0, stream>>>(feat, Wcat, res_b, fsrc, resb, e_src, e_dst);

    dim3 geg((NE+255)/256, 4);
    k_count<<<geg, 256, 0, stream>>>(dst_idx, cnt);
    dim3 gsc((NN+255)/256, 4);
    k_scan1<<<gsc, 256, 0, stream>>>(cnt, bsum);
    k_scan2<<<4, 256, 0, stream>>>(bsum);
    k_scan3<<<gsc, 256, 0, stream>>>(cnt, bsum, row_ptr);
    k_scatter<<<geg, 256, 0, stream>>>(src_idx, dst_idx, e_src, e_dst, row_ptr, cnt2,
                                       src_pack, e_pack);
    dim3 ga((NN+3)/4, 4);
    k_agg<<<ga, 256, 0, stream>>>(row_ptr, src_pack, e_pack, fsrc, resb, res_alpha, out);

    k_cross<<<NN, 256, 0, stream>>>(out, cross_attn);
    k_relout<<<4, 256, 0, stream>>>(rel_emb, prop_W, prop_b, out);
}

// Round 3
// 760.779 us; speedup vs baseline: 4.8837x; 1.5434x over previous
//
#include <hip/hip_runtime.h>
#include <hip/hip_bf16.h>
#include <stdint.h>

typedef unsigned int u32;
typedef unsigned short u16;
typedef short short8 __attribute__((ext_vector_type(8)));
typedef float f32x4 __attribute__((ext_vector_type(4)));

#define NN 50000
#define NE 200000
#define WCT 576     // 256 fsrc | 256 res | 8 e_src | 8 e_dst | 48 pad (cols of C)

__device__ __forceinline__ float leaky(float x){ return x >= 0.f ? x : 0.2f*x; }
__device__ __forceinline__ float bf2f(u16 u){ return __uint_as_float(((u32)u)<<16); }
__device__ __forceinline__ u16 f2bf(float f){            // RNE
    u32 u = __float_as_uint(f);
    u32 r = (u + 0x7fffu + ((u>>16)&1u)) >> 16;
    return (u16)r;
}
// pack 2 floats -> 2 bf16 (truncation) in ONE v_perm_b32
__device__ __forceinline__ u32 pack_bf2(float a, float b){
    return __builtin_amdgcn_perm(__float_as_uint(b), __float_as_uint(a), 0x07060302u);
}
__device__ __forceinline__ int nt_src(int r){ return (r==0)?0:((r==3)?2:1); }
__device__ __forceinline__ int nt_dst(int r){ return (r==1)?0:((r==2)?2:1); }

// ra[r][512] = rel_emb[r] @ rel_W[r]
__global__ void k_ra(const float* __restrict__ rel_emb, const float* __restrict__ rel_W,
                     float* __restrict__ ra){
    int r = blockIdx.x;
    for (int j = threadIdx.x; j < 512; j += blockDim.x){
        float acc = 0.f;
        for (int i = 0; i < 64; i++) acc += rel_emb[r*64+i] * rel_W[(r*64+i)*512 + j];
        ra[r*512 + j] = acc;
    }
}

// Assemble WcatT[r] (576 x 256, bf16, transposed so B-frag reads are K-contiguous):
// rows: [node_W[s] | res_W[d] | w_src_eff(8) | w_dst_eff(8) | 0-pad]
__global__ void k_wcat(const float* __restrict__ node_W, const float* __restrict__ res_W,
                       const float* __restrict__ ra, u16* __restrict__ WcatT){
    int g = blockIdx.x*blockDim.x + threadIdx.x;
    if (g >= 4*WCT*256) return;
    int r = g/(WCT*256); int rem = g%(WCT*256); int n = rem/256; int k = rem%256;
    int s = nt_src(r), d = nt_dst(r);
    float v;
    if (n < 256) v = node_W[(s*256+k)*256 + n];
    else if (n < 512) v = res_W[(d*256+k)*256 + (n-256)];
    else if (n < 520){ // e_src weights: node_W[s]·ra[h, D:]
        int h = n-512; float a = 0.f;
        for (int dd = 0; dd < 32; dd++) a += node_W[(s*256+k)*256 + h*32+dd] * ra[r*512 + h*64+32+dd];
        v = a;
    } else if (n < 528){ // e_dst weights: node_W[d]·ra[h, :D]
        int h = n-520; float a = 0.f;
        for (int dd = 0; dd < 32; dd++) a += node_W[(d*256+k)*256 + h*32+dd] * ra[r*512 + h*64+dd];
        v = a;
    } else v = 0.f;
    WcatT[(size_t)(r*WCT+n)*256 + k] = f2bf(v);
}

// MFMA GEMM: C(NN x 576) = feat[r](fp32->bf16) @ WcatT[r]^T ; epilogue splits outputs.
// BM=128, BN=64, BK=64; 4 waves in 2x2; XOR-swizzled LDS (16B-chunk ^ (row&7)).
__launch_bounds__(256)
__global__ void k_gemm(const float* __restrict__ feat, const u16* __restrict__ WcatT,
                       const float* __restrict__ res_b,
                       u16* __restrict__ fsrc, u16* __restrict__ resb,
                       float* __restrict__ e_src, float* __restrict__ e_dst){
    __shared__ uint4 lsA[1024];   // 128 rows x 8 chunks(16B)
    __shared__ uint4 lsB[512];    // 64 n-rows x 8 chunks(16B)
    const short8* lsA8 = (const short8*)lsA;
    const short8* lsB8 = (const short8*)lsB;

    int r = blockIdx.z;
    int row0 = blockIdx.y*128;
    int n0 = blockIdx.x*64;
    const float* A = feat + (size_t)r*NN*256;
    const u16*   W = WcatT + (size_t)r*WCT*256;

    int t = threadIdx.x;
    int w = t>>6, l = t&63;
    int wm = (w>>1)*64, wn = (w&1)*32;
    int li = l & 15, lg = l >> 4;

    // staging indices
    int arow = t>>1, ahalf = t&1;               // A: row 0..127, 32-elem half
    int ag = row0 + arow; if (ag > NN-1) ag = NN-1;
    const float* asrc = A + (size_t)ag*256 + ahalf*32;
    int bn = t>>2, bc = (t&3)*2;                // B: n-row 0..63, chunk pair
    const u16* bsrc = W + (size_t)(n0+bn)*256 + bc*8;

    f32x4 acc[4][2] = {};
    for (int k0 = 0; k0 < 256; k0 += 64){
        float4 av[8];
        #pragma unroll
        for (int i = 0; i < 8; i++) av[i] = *(const float4*)(asrc + k0 + i*4);
        uint4 bv0 = *(const uint4*)(bsrc + k0);
        uint4 bv1 = *(const uint4*)(bsrc + k0 + 8);
        __syncthreads();
        #pragma unroll
        for (int c = 0; c < 4; c++){
            uint4 pk;
            pk.x = pack_bf2(av[2*c].x,   av[2*c].y);
            pk.y = pack_bf2(av[2*c].z,   av[2*c].w);
            pk.z = pack_bf2(av[2*c+1].x, av[2*c+1].y);
            pk.w = pack_bf2(av[2*c+1].z, av[2*c+1].w);
            int kc = ahalf*4 + c;
            lsA[arow*8 + (kc ^ (arow&7))] = pk;
        }
        lsB[bn*8 + ((bc+0) ^ (bn&7))] = bv0;
        lsB[bn*8 + ((bc+1) ^ (bn&7))] = bv1;
        __syncthreads();
        #pragma unroll
        for (int kk = 0; kk < 2; kk++){
            int kc = kk*4 + lg;
            short8 bfr[2];
            #pragma unroll
            for (int nt = 0; nt < 2; nt++){
                int nrow = wn + nt*16 + li;
                bfr[nt] = lsB8[nrow*8 + (kc ^ (nrow&7))];
            }
            #pragma unroll
            for (int mt = 0; mt < 4; mt++){
                int mrow = wm + mt*16 + li;
                short8 afr = lsA8[mrow*8 + (kc ^ (mrow&7))];
                acc[mt][0] = __builtin_amdgcn_mfma_f32_16x16x32_bf16(afr, bfr[0], acc[mt][0], 0,0,0);
                acc[mt][1] = __builtin_amdgcn_mfma_f32_16x16x32_bf16(afr, bfr[1], acc[mt][1], 0,0,0);
            }
        }
    }
    int d = nt_dst(r);
    #pragma unroll
    for (int mt = 0; mt < 4; mt++){
        #pragma unroll
        for (int nt = 0; nt < 2; nt++){
            #pragma unroll
            for (int q = 0; q < 4; q++){
                int row = row0 + wm + mt*16 + lg*4 + q;
                if (row >= NN) continue;
                int col = n0 + wn + nt*16 + li;
                float v = acc[mt][nt][q];
                size_t nidx = (size_t)r*NN + row;
                if (col < 256)      fsrc[nidx*256 + col] = f2bf(v);
                else if (col < 512) resb[nidx*256 + (col-256)] = f2bf(v + res_b[d*256 + (col-256)]);
                else if (col < 520) e_src[nidx*8 + (col-512)] = v;
                else if (col < 528) e_dst[nidx*8 + (col-520)] = v;
            }
        }
    }
}

// ---- CSR build: count -> hierarchical scan -> scatter ----

__global__ void k_count(const int* __restrict__ dst_idx, u32* __restrict__ cnt){
    int r = blockIdx.y; int e = blockIdx.x*256 + threadIdx.x;
    if (e >= NE) return;
    atomicAdd(&cnt[r*NN + dst_idx[r*NE+e]], 1u);
}

__global__ void k_scan1(const u32* __restrict__ cnt, u32* __restrict__ bsum){
    int r = blockIdx.y, b = blockIdx.x;
    int i = b*256 + threadIdx.x;
    u32 v = (i < NN) ? cnt[r*NN+i] : 0u;
    #pragma unroll
    for (int off = 1; off < 64; off <<= 1) v += __shfl_xor(v, off, 64);
    __shared__ u32 wsum[4];
    int lane = threadIdx.x & 63, w = threadIdx.x >> 6;
    if (lane == 0) wsum[w] = v;
    __syncthreads();
    if (threadIdx.x == 0) bsum[r*256 + b] = wsum[0]+wsum[1]+wsum[2]+wsum[3];
}

__device__ __forceinline__ u32 block_scan_incl(u32 v){
    __shared__ u32 wsum[4];
    int lane = threadIdx.x & 63, w = threadIdx.x >> 6;
    #pragma unroll
    for (int off = 1; off < 64; off <<= 1){
        u32 t = __shfl_up(v, off, 64);
        if (lane >= off) v += t;
    }
    if (lane == 63) wsum[w] = v;
    __syncthreads();
    u32 add = 0;
    #pragma unroll
    for (int k = 0; k < 4; k++) if (k < w) add += wsum[k];
    return v + add;
}

__global__ void k_scan2(u32* __restrict__ bsum){
    int r = blockIdx.x;
    u32 v = bsum[r*256 + threadIdx.x];
    u32 incl = block_scan_incl(v);
    bsum[r*256 + threadIdx.x] = incl - v;
}

__global__ void k_scan3(const u32* __restrict__ cnt, const u32* __restrict__ bsum,
                        u32* __restrict__ row_ptr){
    int r = blockIdx.y, b = blockIdx.x;
    int i = b*256 + threadIdx.x;
    u32 v = (i < NN) ? cnt[r*NN+i] : 0u;
    u32 incl = block_scan_incl(v);
    if (i < NN) row_ptr[r*(NN+1) + i + 1] = bsum[r*256 + b] + incl;
    if (b == 0 && threadIdx.x == 0) row_ptr[r*(NN+1)] = 0u;
}

__global__ void k_scatter(const int* __restrict__ src_idx, const int* __restrict__ dst_idx,
                          const float* __restrict__ e_src, const float* __restrict__ e_dst,
                          const u32* __restrict__ row_ptr, u32* __restrict__ cnt2,
                          u32* __restrict__ src_pack, float* __restrict__ e_pack){
    int r = blockIdx.y; int e = blockIdx.x*256 + threadIdx.x;
    if (e >= NE) return;
    int s = src_idx[r*NE+e], d = dst_idx[r*NE+e];
    u32 pos = row_ptr[r*(NN+1)+d] + atomicAdd(&cnt2[r*NN+d], 1u);
    src_pack[r*NE + pos] = (u32)s;
    const float* es = e_src + ((size_t)r*NN+s)*8;
    const float* ed = e_dst + ((size_t)r*NN+d)*8;
    float* ep = e_pack + ((size_t)(r*NE)+pos)*8;
    #pragma unroll
    for (int h = 0; h < 8; h++) ep[h] = leaky(es[h] + ed[h]);
}

// one wave per (node, rel): inline segment softmax + aggregation + relu + residual gate.
__launch_bounds__(256)
__global__ void k_agg(const u32* __restrict__ row_ptr, const u32* __restrict__ src_pack,
                      const float* __restrict__ e_pack, const u16* __restrict__ fsrc,
                      const u16* __restrict__ resb, const float* __restrict__ res_alpha,
                      float* __restrict__ out){
    int r = blockIdx.y;
    int wid = threadIdx.x >> 6;
    int n = blockIdx.x*4 + wid;
    if (n >= NN) return;
    int l = threadIdx.x & 63;
    u32 p0 = row_ptr[r*(NN+1)+n];
    u32 p1 = row_ptr[r*(NN+1)+n+1];
    int deg = (int)(p1 - p0);

    float m = -1e30f, s = 0.f;
    for (int i = (l>>3); i < deg; i += 8){
        float e = e_pack[((size_t)(r*NE) + p0 + i)*8 + (l&7)];
        float mn = fmaxf(m, e);
        s = s*__expf(m - mn) + __expf(e - mn);
        m = mn;
    }
    #pragma unroll
    for (int msk = 8; msk < 64; msk <<= 1){
        float m2 = __shfl_xor(m, msk, 64);
        float s2 = __shfl_xor(s, msk, 64);
        float mn = fmaxf(m, m2);
        s = s*__expf(m - mn) + s2*__expf(m2 - mn);
        m = mn;
    }
    int h = l >> 3;
    float mh = __shfl(m, h, 64);
    float sh = __shfl(s, h, 64);

    float a0=0.f, a1=0.f, a2=0.f, a3=0.f;
    for (int i = 0; i < deg; i++){
        size_t ep = (size_t)(r*NE) + p0 + i;
        float a = __expf(e_pack[ep*8 + h] - mh) / sh;
        u32 src = src_pack[ep];
        ushort4 f = *(const ushort4*)(fsrc + ((size_t)r*NN+src)*256 + l*4);
        a0 += bf2f(f.x)*a; a1 += bf2f(f.y)*a; a2 += bf2f(f.z)*a; a3 += bf2f(f.w)*a;
    }
    int d = nt_dst(r);
    float alpha = 1.f/(1.f + __expf(-res_alpha[d]));
    float beta = 1.f - alpha;
    ushort4 rv = *(const ushort4*)(resb + ((size_t)r*NN+n)*256 + l*4);
    float4 o;
    o.x = fmaxf(a0,0.f)*alpha + bf2f(rv.x)*beta;
    o.y = fmaxf(a1,0.f)*alpha + bf2f(rv.y)*beta;
    o.z = fmaxf(a2,0.f)*alpha + bf2f(rv.z)*beta;
    o.w = fmaxf(a3,0.f)*alpha + bf2f(rv.w)*beta;
    *(float4*)(out + ((size_t)r*NN+n)*256 + l*4) = o;
}

__global__ void k_cross(float* __restrict__ out, const float* __restrict__ cross_attn){
    int n = blockIdx.x; int t = threadIdx.x;   // t = h*32 + d
    size_t i0 = (size_t)n*256 + t;
    size_t i3 = (size_t)3*NN*256 + (size_t)n*256 + t;
    float v0 = out[i0], v3 = out[i3];
    float ca0 = cross_attn[t];
    float ca3 = cross_attn[3*256 + t];
    float p00 = v0*ca0, p30 = v3*ca0, p03 = v0*ca3, p33 = v3*ca3;
    #pragma unroll
    for (int m = 16; m >= 1; m >>= 1){
        p00 += __shfl_xor(p00, m, 64);
        p30 += __shfl_xor(p30, m, 64);
        p03 += __shfl_xor(p03, m, 64);
        p33 += __shfl_xor(p33, m, 64);
    }
    float l0 = leaky(p00), l3 = leaky(p30);
    float mm = fmaxf(l0, l3);
    float w0 = __expf(l0-mm), w3 = __expf(l3-mm);
    float o0 = (w0*v0 + w3*v3) / (w0+w3);
    float q0 = leaky(p03), q3 = leaky(p33);
    float mq = fmaxf(q0, q3);
    float u0 = __expf(q0-mq), u3 = __expf(q3-mq);
    float o3 = (u0*v0 + u3*v3) / (u0+u3);
    out[i0] = o0; out[i3] = o3;
}

__global__ void k_relout(const float* __restrict__ rel_emb, const float* __restrict__ prop_W,
                         const float* __restrict__ prop_b, float* __restrict__ out){
    int r = blockIdx.x; int o = threadIdx.x;
    float acc = prop_b[r*256 + o];
    for (int i = 0; i < 64; i++) acc += rel_emb[r*64+i] * prop_W[(r*64+i)*256 + o];
    out[(size_t)4*NN*256 + r*256 + o] = acc;
}

extern "C" void kernel_launch(void* const* d_in, const int* in_sizes, int n_in,
                              void* d_out, int out_size, void* d_ws, size_t ws_size,
                              hipStream_t stream){
    const float* feat      = (const float*)d_in[0];
    const float* rel_emb   = (const float*)d_in[1];
    const float* node_W    = (const float*)d_in[2];
    const float* rel_W     = (const float*)d_in[3];
    const float* res_W     = (const float*)d_in[4];
    const float* res_b     = (const float*)d_in[5];
    const float* res_alpha = (const float*)d_in[6];
    const float* cross_attn= (const float*)d_in[7];
    const float* prop_W    = (const float*)d_in[8];
    const float* prop_b    = (const float*)d_in[9];
    const int* src_idx     = (const int*)d_in[10];
    const int* dst_idx     = (const int*)d_in[11];
    float* out = (float*)d_out;

    char* ws = (char*)d_ws;
    u32*   cnt     = (u32*)  (ws);                 //    800,000 B (4,NN)
    u32*   cnt2    = (u32*)  (ws + 800000);        //    800,000 B (4,NN)
    u32*   bsum    = (u32*)  (ws + 1600000);       //      4,096 B (4,256)
    u32*   row_ptr = (u32*)  (ws + 1604096);       //    800,016 B (4,NN+1)
    float* ra      = (float*)(ws + 2404112);       //      8,192 B (4,512)
    u16*   WcatT   = (u16*)  (ws + 2412304);       //  1,179,648 B (4,576,256) bf16
    float* e_src   = (float*)(ws + 4771600);       //  6,400,000 B (4,NN,8)
    float* e_dst   = (float*)(ws + 11171600);      //  6,400,000 B (4,NN,8)
    u32*   src_pack= (u32*)  (ws + 17571600);      //  3,200,000 B (4,NE)
    float* e_pack  = (float*)(ws + 20771600);      // 25,600,000 B (4,NE,8)
    u16*   fsrc    = (u16*)  (ws + 46371600);      //102,400,000 B (4,NN,256) bf16
    u16*   resb    = (u16*)  (ws + 148771600);     //102,400,000 B (4,NN,256) bf16
    // total: 251,171,600 B

    hipMemsetAsync(cnt, 0, 1604096, stream);  // cnt + cnt2 + bsum

    k_ra<<<4, 256, 0, stream>>>(rel_emb, rel_W, ra);
    k_wcat<<<(4*WCT*256)/256, 256, 0, stream>>>(node_W, res_W, ra, WcatT);
    dim3 gg(WCT/64, (NN+127)/128, 4);
    k_gemm<<<gg, 256, 0, stream>>>(feat, WcatT, res_b, fsrc, resb, e_src, e_dst);

    dim3 geg((NE+255)/256, 4);
    k_count<<<geg, 256, 0, stream>>>(dst_idx, cnt);
    dim3 gsc((NN+255)/256, 4);
    k_scan1<<<gsc, 256, 0, stream>>>(cnt, bsum);
    k_scan2<<<4, 256, 0, stream>>>(bsum);
    k_scan3<<<gsc, 256, 0, stream>>>(cnt, bsum, row_ptr);
    k_scatter<<<geg, 256, 0, stream>>>(src_idx, dst_idx, e_src, e_dst, row_ptr, cnt2,
                                       src_pack, e_pack);
    dim3 ga((NN+3)/4, 4);
    k_agg<<<ga, 256, 0, stream>>>(row_ptr, src_pack, e_pack, fsrc, resb, res_alpha, out);

    k_cross<<<NN, 256, 0, stream>>>(out, cross_attn);
    k_relout<<<4, 256, 0, stream>>>(rel_emb, prop_W, prop_b, out);
}